// Round 1
// baseline (1622.959 us; speedup 1.0000x reference)
//
#include <hip/hip_runtime.h>

#define Hdim 512
#define Wdim 512
#define Cdim 64
#define TH 8
#define TW 32
#define IH (TH + 4)   // 12
#define IW (TW + 4)   // 36
#define HWSZ (Hdim * Wdim)

__device__ __forceinline__ int reflect_idx(int i) {
    i = abs(i);
    if (i >= Hdim) i = 2 * Hdim - 2 - i;
    return i;
}

__device__ __forceinline__ float gelu_exact(float v) {
    return 0.5f * v * (1.0f + erff(v * 0.70710678118654752f));
}

// MODE 0: out = md ? gelu(conv(xin)+b) : xres        (write all pixels)
// MODE 1: if (sd) out = gelu(conv(xin)+b) + xres     (masked store)
template <int MODE>
__global__ __launch_bounds__(256) void conv_k(
    const float* __restrict__ xin,
    const float* __restrict__ xres,
    const float* __restrict__ mask,
    const float* __restrict__ wgt,   // (64,64,3,3) OIHW
    const float* __restrict__ bias,  // (64,)
    float* __restrict__ out)
{
    __shared__ float sx[4][IH][IW];
    __shared__ float sm[IH][IW];

    const int tid = threadIdx.x;
    const int bx  = blockIdx.x & 15;        // Wdim/TW = 16
    const int by  = blockIdx.x >> 4;        // Hdim/TH = 64
    const int ox0 = bx * TW, oy0 = by * TH;
    const int lx  = tid & 31, ly = tid >> 5;
    const int oh  = oy0 + ly, ow = ox0 + lx;
    const int pix = oh * Wdim + ow;

    bool active;
    if (MODE == 0) {
        // stage mask tile (zero outside: identity for max of {0,1})
        for (int i = tid; i < IH * IW; i += 256) {
            int r = oy0 - 2 + i / IW;
            int c = ox0 - 2 + i % IW;
            float m = 0.0f;
            if (r >= 0 && r < Hdim && c >= 0 && c < Wdim) m = mask[r * Wdim + c];
            sm[i / IW][i % IW] = m;
        }
        __syncthreads();
        float md = 0.0f;
        #pragma unroll
        for (int dy = 0; dy < 5; ++dy)
            #pragma unroll
            for (int dx = 0; dx < 5; ++dx)
                md = fmaxf(md, sm[ly + dy][lx + dx]);
        active = md > 0.5f;
    } else {
        active = mask[pix] > 0.5f;
    }

    float acc[Cdim];
    #pragma unroll
    for (int o = 0; o < Cdim; ++o) acc[o] = bias[o];

    for (int cc = 0; cc < Cdim; cc += 4) {
        __syncthreads();
        for (int i = tid; i < 4 * IH * IW; i += 256) {
            int ch  = i / (IH * IW);
            int rem = i - ch * (IH * IW);
            int r = reflect_idx(oy0 - 2 + rem / IW);
            int c = reflect_idx(ox0 - 2 + rem % IW);
            (&sx[0][0][0])[i] = xin[(size_t)(cc + ch) * HWSZ + r * Wdim + c];
        }
        __syncthreads();

        #pragma unroll
        for (int ch = 0; ch < 4; ++ch) {
            float in[9];
            #pragma unroll
            for (int a = 0; a < 3; ++a)
                #pragma unroll
                for (int b = 0; b < 3; ++b)
                    in[a * 3 + b] = sx[ch][ly + 2 * a][lx + 2 * b];
            const float* wp = wgt + (cc + ch) * 9;  // wgt[o][ci][t]: o-stride 576
            #pragma unroll
            for (int o = 0; o < Cdim; ++o) {
                float s = acc[o];
                #pragma unroll
                for (int t = 0; t < 9; ++t)
                    s = fmaf(in[t], wp[o * 576 + t], s);
                acc[o] = s;
            }
        }
    }

    if (MODE == 0) {
        #pragma unroll
        for (int o = 0; o < Cdim; ++o) {
            float v = active ? gelu_exact(acc[o]) : xres[(size_t)o * HWSZ + pix];
            out[(size_t)o * HWSZ + pix] = v;
        }
    } else {
        if (active) {
            #pragma unroll
            for (int o = 0; o < Cdim; ++o)
                out[(size_t)o * HWSZ + pix] = gelu_exact(acc[o]) + xres[(size_t)o * HWSZ + pix];
        }
    }
}

// depthwise 3x3 dil-2 conv on x, gelu, +x, store where !sd
__global__ __launch_bounds__(256) void dw_k(
    const float* __restrict__ x,
    const float* __restrict__ mask,
    const float* __restrict__ w3,   // (64,1,3,3)
    const float* __restrict__ b3,
    float* __restrict__ out)
{
    __shared__ float sx[4][IH][IW];

    const int tid = threadIdx.x;
    const int bx  = blockIdx.x & 15;
    const int by  = blockIdx.x >> 4;
    const int ox0 = bx * TW, oy0 = by * TH;
    const int lx  = tid & 31, ly = tid >> 5;
    const int oh  = oy0 + ly, ow = ox0 + lx;
    const int pix = oh * Wdim + ow;

    const bool inactive = !(mask[pix] > 0.5f);

    for (int cc = 0; cc < Cdim; cc += 4) {
        __syncthreads();
        for (int i = tid; i < 4 * IH * IW; i += 256) {
            int ch  = i / (IH * IW);
            int rem = i - ch * (IH * IW);
            int r = reflect_idx(oy0 - 2 + rem / IW);
            int c = reflect_idx(ox0 - 2 + rem % IW);
            (&sx[0][0][0])[i] = x[(size_t)(cc + ch) * HWSZ + r * Wdim + c];
        }
        __syncthreads();
        if (inactive) {
            #pragma unroll
            for (int ch = 0; ch < 4; ++ch) {
                float s = b3[cc + ch];
                const float* wp = w3 + (cc + ch) * 9;
                #pragma unroll
                for (int a = 0; a < 3; ++a)
                    #pragma unroll
                    for (int b = 0; b < 3; ++b)
                        s = fmaf(sx[ch][ly + 2 * a][lx + 2 * b], wp[a * 3 + b], s);
                float xc = sx[ch][ly + 2][lx + 2];
                out[(size_t)(cc + ch) * HWSZ + pix] = gelu_exact(s) + xc;
            }
        }
    }
}

extern "C" void kernel_launch(void* const* d_in, const int* in_sizes, int n_in,
                              void* d_out, int out_size, void* d_ws, size_t ws_size,
                              hipStream_t stream) {
    const float* x    = (const float*)d_in[0];
    const float* mask = (const float*)d_in[1];
    const float* w1   = (const float*)d_in[2];
    const float* b1   = (const float*)d_in[3];
    const float* w2   = (const float*)d_in[4];
    const float* b2   = (const float*)d_in[5];
    const float* w3   = (const float*)d_in[6];
    const float* b3   = (const float*)d_in[7];
    float* out  = (float*)d_out;
    float* xori = (float*)d_ws;   // 64 MB scratch: x_ori

    const int nblk = (Hdim / TH) * (Wdim / TW);  // 64*16 = 1024

    // x_ori = where(md, gelu(conv1(x)+b1), x)
    conv_k<0><<<nblk, 256, 0, stream>>>(x, x, mask, w1, b1, xori);
    // out[sd] = gelu(conv2(x_ori)+b2) + x
    conv_k<1><<<nblk, 256, 0, stream>>>(xori, x, mask, w2, b2, out);
    // out[!sd] = gelu(dw(x,w3)+b3) + x
    dw_k<<<nblk, 256, 0, stream>>>(x, mask, w3, b3, out);
}

// Round 2
// 354.866 us; speedup vs baseline: 4.5734x; 4.5734x over previous
//
#include <hip/hip_runtime.h>

#define Hdim 512
#define Wdim 512
#define Cdim 64
#define HWSZ (Hdim * Wdim)
#define TH 8
#define TW 32
#define IH 12
#define IW 36
#define NL (IH * IW)   // 432 input-tile pixels

typedef __attribute__((ext_vector_type(8))) short short8;    // 8 bf16 (4 VGPR) MFMA frag
typedef __attribute__((ext_vector_type(4))) float f32x4;
typedef __attribute__((ext_vector_type(4))) int   i32x4;

__device__ __forceinline__ int reflect_idx(int i) {
    i = abs(i);
    if (i >= Hdim) i = 2 * Hdim - 2 - i;
    return i;
}

__device__ __forceinline__ unsigned bf16_1(float f) {
    unsigned u = __float_as_uint(f);
    return (u + 0x7FFF + ((u >> 16) & 1)) >> 16;   // RNE
}
__device__ __forceinline__ unsigned bf16pk(float lo, float hi) {
    return bf16_1(lo) | (bf16_1(hi) << 16);
}
// tanh-form GELU via sigmoid: max abs err ~1e-3 << 0.1425 threshold
__device__ __forceinline__ float gelu_fast(float v) {
    float u = v * fmaf(v * v, 0.0713548162726f, 1.59576912161f);
    float e = __expf(-u);
    return v / (1.0f + e);
}

// MODE 0: in = x fp32 NCHW (transpose+cvt staging); out = xori bf16 NHWC (all pixels,
//         md ? gelu(conv1) : x), md = 5x5 dilate of mask, computed in-kernel.
// MODE 1: in = xori bf16 NHWC (direct staging); out = fp32 NCHW, only where sd,
//         value = gelu(conv2) + x.
template <int MODE>
__global__ __launch_bounds__(256, 2) void mconv(
    const float* __restrict__ xin_f,
    const unsigned short* __restrict__ xin_t,
    const float* __restrict__ mask,
    const float* __restrict__ wgt,    // (64,64,3,3) fp32 OIHW
    const float* __restrict__ bias,   // (64,)
    const float* __restrict__ xres,   // x fp32 NCHW
    unsigned short* __restrict__ out_t,
    float* __restrict__ out_f)
{
    __shared__ unsigned char sx[NL * 80];        // 34560 B: [L][4 chunks x16B + 16B pad]
    __shared__ unsigned char wlds[5 * 4 * 1024]; // 20480 B: up to 5 taps x 4 fr frags
    __shared__ float smask[NL];                  // 1728 B (MODE 0)

    const int tid  = threadIdx.x;
    const int lane = tid & 63;
    const int wv   = tid >> 6;
    const int bx   = blockIdx.x & 15;
    const int by   = blockIdx.x >> 4;
    const int ox0  = bx * TW, oy0 = by * TH;

    // ---- accumulators init with bias: C row (co) = fr*16 + (lane>>4)*4 + r ----
    f32x4 acc[4][4];
    #pragma unroll
    for (int fr = 0; fr < 4; ++fr) {
        f32x4 b;
        #pragma unroll
        for (int r = 0; r < 4; ++r) b[r] = bias[fr * 16 + (lane >> 4) * 4 + r];
        #pragma unroll
        for (int fc = 0; fc < 4; ++fc) acc[fr][fc] = b;
    }

    if (MODE == 0) {
        for (int i = tid; i < NL; i += 256) {
            int r = oy0 - 2 + i / IW, c = ox0 - 2 + (i - (i / IW) * IW);
            float m = 0.0f;
            if (r >= 0 && r < Hdim && c >= 0 && c < Wdim) m = mask[r * Wdim + c];
            smask[i] = m;
        }
    }

    // ---- staging helpers ----
    auto stage_input = [&](int h) __attribute__((always_inline)) {
        if (MODE == 0) {
            // transpose fp32 NCHW -> bf16 [L][ci-contig], conflict-free b32 writes
            int s  = (lane >> 3) & 3;                 // ci-pair slot in chunk
            int Lo = (lane & 7) + ((lane >> 5) << 3);
            #pragma unroll
            for (int it = 0; it < 7; ++it) {
                int L = it * 64 + wv * 16 + Lo;
                if (L < NL) {
                    int r  = reflect_idx(oy0 - 2 + L / IW);
                    int c  = reflect_idx(ox0 - 2 + (L - (L / IW) * IW));
                    int gp = r * Wdim + c;
                    #pragma unroll
                    for (int jk = 0; jk < 4; ++jk) {
                        int ci = h * 32 + jk * 8 + s * 2;
                        float f0 = xin_f[ci * HWSZ + gp];
                        float f1 = xin_f[(ci + 1) * HWSZ + gp];
                        *(unsigned*)&sx[L * 80 + jk * 16 + s * 4] = bf16pk(f0, f1);
                    }
                }
            }
        } else {
            // direct bf16 16B-chunk copies
            #pragma unroll
            for (int it = 0; it < 7; ++it) {
                int L  = it * 64 + wv * 16 + (lane >> 2);
                int jk = lane & 3;
                if (L < NL) {
                    int r  = reflect_idx(oy0 - 2 + L / IW);
                    int c  = reflect_idx(ox0 - 2 + (L - (L / IW) * IW));
                    int gp = r * Wdim + c;
                    i32x4 v = *(const i32x4*)&xin_t[gp * 64 + h * 32 + jk * 8];
                    *(i32x4*)&sx[L * 80 + jk * 16] = v;
                }
            }
        }
    };

    auto stage_w = [&](int h, int t0, int nt) __attribute__((always_inline)) {
        for (int q = tid; q < nt * 256; q += 256) {
            int f = q >> 6, l = q & 63;
            int tt = f >> 2, fr = f & 3;
            int co = fr * 16 + (l & 15);
            int ci = h * 32 + ((l >> 4) << 3);
            const float* wp = wgt + (co * 64 + ci) * 9 + (t0 + tt);
            i32x4 v;
            v.x = bf16pk(wp[0],  wp[9]);
            v.y = bf16pk(wp[18], wp[27]);
            v.z = bf16pk(wp[36], wp[45]);
            v.w = bf16pk(wp[54], wp[63]);
            *(i32x4*)&wlds[q * 16] = v;
        }
    };

    auto compute = [&](int t0, int nt) __attribute__((always_inline)) {
        #pragma unroll
        for (int tt = 0; tt < nt; ++tt) {
            int t = t0 + tt;
            int dy = (t / 3) * 2, dx = (t - (t / 3) * 3) * 2;
            short8 af[4], bfr[4];
            #pragma unroll
            for (int fr = 0; fr < 4; ++fr)
                af[fr] = *(const short8*)&wlds[(tt * 4 + fr) * 1024 + lane * 16];
            #pragma unroll
            for (int fc = 0; fc < 4; ++fc) {
                int pr = 2 * wv + (fc >> 1);
                int pc = (fc & 1) * 16 + (lane & 15);
                int L  = (pr + dy) * IW + pc + dx;
                bfr[fc] = *(const short8*)&sx[L * 80 + (lane >> 4) * 16];
            }
            #pragma unroll
            for (int fr = 0; fr < 4; ++fr)
                #pragma unroll
                for (int fc = 0; fc < 4; ++fc)
                    acc[fr][fc] = __builtin_amdgcn_mfma_f32_16x16x32_bf16(
                        af[fr], bfr[fc], acc[fr][fc], 0, 0, 0);
        }
    };

    // ---- main schedule: 2 ci-halves x (5+4 taps) ----
    stage_input(0); stage_w(0, 0, 5);
    __syncthreads();
    compute(0, 5);
    __syncthreads();
    stage_w(0, 5, 4);
    __syncthreads();
    compute(5, 4);
    __syncthreads();
    stage_input(1); stage_w(1, 0, 5);
    __syncthreads();
    compute(0, 5);
    __syncthreads();
    stage_w(1, 5, 4);
    __syncthreads();
    compute(5, 4);

    // ---- epilogue ----
    if (MODE == 0) {
        // md for wave pixel == lane
        float mdv;
        {
            int pr = 2 * wv + (lane >> 5), pc = lane & 31;
            float m = 0.0f;
            #pragma unroll
            for (int dy = 0; dy < 5; ++dy)
                #pragma unroll
                for (int dx = 0; dx < 5; ++dx)
                    m = fmaxf(m, smask[(pr + dy) * IW + pc + dx]);
            mdv = m;
        }
        __syncthreads();   // free sx for per-wave bounce
        unsigned char* bounce = sx + wv * 8192;
        #pragma unroll
        for (int fc = 0; fc < 4; ++fc) {
            float msel = __shfl(mdv, fc * 16 + (lane & 15), 64);
            bool md = msel > 0.5f;
            int p = fc * 16 + (lane & 15);
            int gpix = (oy0 + 2 * wv + (p >> 5)) * Wdim + ox0 + (p & 31);
            int g = lane >> 4;
            #pragma unroll
            for (int fr = 0; fr < 4; ++fr) {
                int co0 = fr * 16 + g * 4;
                unsigned pk0, pk1;
                if (md) {
                    pk0 = bf16pk(gelu_fast(acc[fr][fc][0]), gelu_fast(acc[fr][fc][1]));
                    pk1 = bf16pk(gelu_fast(acc[fr][fc][2]), gelu_fast(acc[fr][fc][3]));
                } else {
                    pk0 = bf16pk(xres[(co0 + 0) * HWSZ + gpix], xres[(co0 + 1) * HWSZ + gpix]);
                    pk1 = bf16pk(xres[(co0 + 2) * HWSZ + gpix], xres[(co0 + 3) * HWSZ + gpix]);
                }
                int cj = fr * 2 + (g >> 1);
                int bo = p * 128 + ((cj ^ (p & 7)) * 16) + (g & 1) * 8;
                *(unsigned*)&bounce[bo]     = pk0;
                *(unsigned*)&bounce[bo + 4] = pk1;
            }
        }
        __syncthreads();   // bounce visible (also orders within wave)
        #pragma unroll
        for (int q = 0; q < 8; ++q) {
            int m   = (q & 3) * 64 + lane;     // 16B chunk in 4KB row-half
            int row = 2 * wv + (q >> 2);
            int pp  = (q >> 2) * 32 + (m >> 3);
            int j   = m & 7;
            i32x4 v = *(const i32x4*)&bounce[pp * 128 + ((j ^ (pp & 7)) * 16)];
            *(i32x4*)&out_t[((size_t)((oy0 + row) * Wdim + ox0)) * 64 + m * 8] = v;
        }
    } else {
        #pragma unroll
        for (int fc = 0; fc < 4; ++fc) {
            int p = fc * 16 + (lane & 15);
            int gpix = (oy0 + 2 * wv + (p >> 5)) * Wdim + ox0 + (p & 31);
            bool sd = mask[gpix] > 0.5f;
            if (sd) {
                #pragma unroll
                for (int fr = 0; fr < 4; ++fr) {
                    int co0 = fr * 16 + (lane >> 4) * 4;
                    #pragma unroll
                    for (int r = 0; r < 4; ++r) {
                        float v = gelu_fast(acc[fr][fc][r]) + xres[(co0 + r) * HWSZ + gpix];
                        out_f[(co0 + r) * HWSZ + gpix] = v;
                    }
                }
            }
        }
    }
}

// depthwise 3x3 dil-2 + gelu + residual, stored where !sd; per-pixel, no LDS
__global__ __launch_bounds__(256) void dwk(
    const float* __restrict__ x, const float* __restrict__ mask,
    const float* __restrict__ w3, const float* __restrict__ b3,
    float* __restrict__ out)
{
    int pix = blockIdx.x * 256 + threadIdx.x;
    int r = pix >> 9, c = pix & 511;
    if (mask[pix] > 0.5f) return;
    int ro[3] = { reflect_idx(r - 2) * Wdim, r * Wdim, reflect_idx(r + 2) * Wdim };
    int co[3] = { reflect_idx(c - 2), c, reflect_idx(c + 2) };
    for (int ci = 0; ci < Cdim; ++ci) {
        const float* xp = x + ci * HWSZ;
        const float* wp = w3 + ci * 9;
        float s = b3[ci];
        float xc = 0.0f;
        #pragma unroll
        for (int a = 0; a < 3; ++a)
            #pragma unroll
            for (int b = 0; b < 3; ++b) {
                float xv = xp[ro[a] + co[b]];
                if (a == 1 && b == 1) xc = xv;
                s = fmaf(xv, wp[a * 3 + b], s);
            }
        out[ci * HWSZ + pix] = gelu_fast(s) + xc;
    }
}

extern "C" void kernel_launch(void* const* d_in, const int* in_sizes, int n_in,
                              void* d_out, int out_size, void* d_ws, size_t ws_size,
                              hipStream_t stream) {
    const float* x    = (const float*)d_in[0];
    const float* mask = (const float*)d_in[1];
    const float* w1   = (const float*)d_in[2];
    const float* b1   = (const float*)d_in[3];
    const float* w2   = (const float*)d_in[4];
    const float* b2   = (const float*)d_in[5];
    const float* w3   = (const float*)d_in[6];
    const float* b3   = (const float*)d_in[7];
    float* out = (float*)d_out;
    unsigned short* xori = (unsigned short*)d_ws;   // 32 MB bf16 NHWC

    const int nblk = (Hdim / TH) * (Wdim / TW);     // 1024

    mconv<0><<<nblk, 256, 0, stream>>>(x, nullptr, mask, w1, b1, x, xori, nullptr);
    mconv<1><<<nblk, 256, 0, stream>>>(nullptr, xori, mask, w2, b2, x, nullptr, out);
    dwk<<<HWSZ / 256, 256, 0, stream>>>(x, mask, w3, b3, out);
}